// Round 6
// baseline (833.611 us; speedup 1.0000x reference)
//
#include <hip/hip_runtime.h>

#define VOX (128*128*32)   // 524288 voxels
#define CCH 64
#define NCL 20
#define DD 128
#define HH 128
#define WW 32
#define ZT 8
#define EPSV 1e-5f
#define THRESV 0.2f

// ---- order-preserving float <-> uint key for atomic min/max ----
__device__ __forceinline__ unsigned keyOf(float f){
    unsigned u = __float_as_uint(f);
    return (u & 0x80000000u) ? ~u : (u | 0x80000000u);
}
__device__ __forceinline__ float keyInv(unsigned k){
    unsigned u = (k & 0x80000000u) ? (k & 0x7fffffffu) : ~k;
    return __uint_as_float(u);
}

__global__ void k_init(unsigned* keys){
    int i = threadIdx.x;
    if (i < NCL){ keys[i] = 0xFFFFFFFFu; keys[NCL+i] = 0u; }
}

// ---- Pass A: logit (einsum + bias), softmax masks, per-voxel mean/max over C ----
__global__ __launch_bounds__(256) void k_logit_softmax(
    const float* __restrict__ x, const float* __restrict__ clsw,
    const float* __restrict__ clsb, float* __restrict__ masks,
    float* __restrict__ logit, float* __restrict__ mx, float* __restrict__ Mx)
{
    __shared__ float sw[NCL*CCH];
    __shared__ float sb[NCL];
    int tid = threadIdx.x;
    for (int q = tid; q < NCL*CCH; q += 256) sw[q] = clsw[q];
    if (tid < NCL) sb[tid] = clsb[tid];
    __syncthreads();
    int v = blockIdx.x*256 + tid;
    float acc[NCL];
    #pragma unroll
    for (int o=0;o<NCL;o++) acc[o] = sb[o];
    float s = 0.f, mm = -1e30f;
    for (int c=0;c<CCH;c++){
        float xv = x[c*VOX + v];
        s += xv; mm = fmaxf(mm, xv);
        #pragma unroll
        for (int o=0;o<NCL;o++) acc[o] = fmaf(xv, sw[o*CCH + c], acc[o]);
    }
    mx[v] = s * (1.f/64.f);
    Mx[v] = mm;
    float lm = acc[0];
    #pragma unroll
    for (int o=1;o<NCL;o++) lm = fmaxf(lm, acc[o]);
    float es = 0.f;
    #pragma unroll
    for (int o=0;o<NCL;o++){
        logit[o*VOX + v] = acc[o];
        float e = expf(acc[o] - lm);
        es += e; acc[o] = e;
    }
    float inv = 1.f/es;
    #pragma unroll
    for (int o=0;o<NCL;o++) masks[o*VOX + v] = acc[o]*inv;
}

// ---- Pass B: z-marching FIR conv, async global_load_lds double-buffered staging ----
// block = 128 thr: y = tid>>2 (32 rows), x0 = (tid&3)*8. grid (20 cls, 16 z, 4 y) = 1280 = 5/CU.
// LDS: 2 buf x 3 raw planes (mask, mx, Mx), plane = 40 rows x 32 dw, quad-XOR swizzled.
// Counted vmcnt (wave0:8, wave1:7 staging instrs/slice), raw s_barrier, products at consume.
// Writes RAW conv accumulator to G; sigmoid/heat/minmax done by k_heat.

#define F8(AL,AH,WV,q0,q1,q2,q3,q4,q5,q6,q7) { \
    AL.x=fmaf(q0,WV,AL.x); AL.y=fmaf(q1,WV,AL.y); AL.z=fmaf(q2,WV,AL.z); AL.w=fmaf(q3,WV,AL.w); \
    AH.x=fmaf(q4,WV,AH.x); AH.y=fmaf(q5,WV,AH.y); AH.z=fmaf(q6,WV,AH.z); AH.w=fmaf(q7,WV,AH.w); }

#define DZ8(AL,AH,WP,P) { \
    F8(AL,AH,(WP)[0], P##1,P##2,P##3,P##4,P##5,P##6,P##7,P##8) \
    F8(AL,AH,(WP)[1], P##2,P##3,P##4,P##5,P##6,P##7,P##8,P##9) \
    F8(AL,AH,(WP)[2], P##3,P##4,P##5,P##6,P##7,P##8,P##9,P##10) \
    F8(AL,AH,(WP)[3], P##4,P##5,P##6,P##7,P##8,P##9,P##10,P##11) \
    F8(AL,AH,(WP)[4], P##5,P##6,P##7,P##8,P##9,P##10,P##11,P##12) \
    F8(AL,AH,(WP)[5], P##6,P##7,P##8,P##9,P##10,P##11,P##12,P##13) \
    F8(AL,AH,(WP)[6], P##7,P##8,P##9,P##10,P##11,P##12,P##13,P##14) }

#define TGROUP(P, WT) { \
    const float* wd_ = (WT) + dy*7; \
    if (ok6) DZ8(a6l,a6h, wd_+0,   P) \
    if (ok5) DZ8(a5l,a5h, wd_+49,  P) \
    if (ok4) DZ8(a4l,a4h, wd_+98,  P) \
    if (ok3) DZ8(a3l,a3h, wd_+147, P) \
    if (ok2) DZ8(a2l,a2h, wd_+196, P) \
    if (ok1) DZ8(a1l,a1h, wd_+245, P) \
    if (ok0) DZ8(a0l,a0h, wd_+294, P) }

#define PLANE_F 1280     // floats per plane (40 rows x 32)
#define SLICE_F 3840     // 3 planes
#define LDS_F   7680     // 2 buffers

__device__ __forceinline__ void issue_slice(const float* mk, const float* mxp, const float* Mxp,
        float* FLf, int bufF, int zi, int y0, int lane, int wid)
{
    const int zc = min(max(zi, 0), DD-1);
    const float* srcs[3] = { mk, mxp, Mxp };
    #pragma unroll
    for (int k = 0; k < 15; ++k){
        const int f = k/5, i = k%5;
        if ((k < 8) != (wid == 0)) continue;   // wave0: k0..7, wave1: k8..14
        int Q   = i*64 + lane;
        int row = Q >> 3, xq = Q & 7;
        int gy  = y0 - 3 + row;
        bool ok = (row < 38) && ((unsigned)gy < (unsigned)HH);
        if (ok){
            const float* g = srcs[f] + (((size_t)(zc*HH + gy)*8 + (xq ^ (row & 7))) << 2);
            float* l = FLf + bufF + f*PLANE_F + i*256;   // wave-uniform; HW adds lane*16B
            __builtin_amdgcn_global_load_lds(
                (const __attribute__((address_space(1))) void*)g,
                (__attribute__((address_space(3))) void*)l, 16, 0, 0);
        }
    }
}

__global__ __launch_bounds__(128, 3) void k_conv6(const float* __restrict__ masksAll,
        const float* __restrict__ mxp, const float* __restrict__ Mxp,
        const float* __restrict__ cfr, float* __restrict__ G)
{
    __shared__ __align__(16) float FLf[LDS_F];
    const int cls = blockIdx.x;
    const int z0  = blockIdx.y * ZT;
    const int y0  = blockIdx.z * 32;
    const int tid = threadIdx.x;
    const int lane = tid & 63, wid = tid >> 6;
    const int y  = tid >> 2;          // 0..31
    const int xg = tid & 3;
    const int x0 = xg * 8;
    const bool lo_inv = (xg == 0), hi_inv = (xg == 3);
    const float* mk   = masksAll + (size_t)cls * VOX;
    const float* wcls = cfr + cls*1029;          // uniform -> scalar loads
    float* Gc = G + (size_t)cls * VOX;

    // pre-zero LDS (borders/pads rely on this; loads never write masked slots)
    for (int q = tid; q < LDS_F/4; q += 128) *(float4*)(FLf + q*4) = make_float4(0.f,0.f,0.f,0.f);
    __syncthreads();

    issue_slice(mk, mxp, Mxp, FLf, 0,       z0-3, y0, lane, wid);
    issue_slice(mk, mxp, Mxp, FLf, SLICE_F, z0-2, y0, lane, wid);

    float4 a0l{},a0h{},a1l{},a1h{},a2l{},a2h{},a3l{},a3h{},
           a4l{},a4h{},a5l{},a5h{},a6l{},a6h{};
    int cur = 0;

    #pragma unroll 1
    for (int zi = z0 - 3; zi <= z0 + ZT + 2; ++zi){
        // wait for slice zi (leave newest K = slice zi+1 in flight), then join
        if (wid == 0) { asm volatile("s_waitcnt vmcnt(8)" ::: "memory"); }
        else          { asm volatile("s_waitcnt vmcnt(7)" ::: "memory"); }
        __builtin_amdgcn_sched_barrier(0);
        __builtin_amdgcn_s_barrier();
        __builtin_amdgcn_sched_barrier(0);

        if ((unsigned)zi >= (unsigned)DD){
            // z-OOB slice: overwrite buffer with zeros (rare: edge z-tiles only)
            float4 z4 = make_float4(0.f,0.f,0.f,0.f);
            for (int q = tid; q < SLICE_F/4; q += 128) *(float4*)(FLf + cur*SLICE_F + q*4) = z4;
            __syncthreads();
        }

        const int lo = z0 + 3 - zi;                // okJ: J>=lo && J-lo<ZT (wave-uniform)
        const bool ok0 = (0>=lo) && (0-lo<ZT);
        const bool ok1 = (1>=lo) && (1-lo<ZT);
        const bool ok2 = (2>=lo) && (2-lo<ZT);
        const bool ok3 = (3>=lo) && (3-lo<ZT);
        const bool ok4 = (4>=lo) && (4-lo<ZT);
        const bool ok5 = (5>=lo) && (5-lo<ZT);
        const bool ok6 = (6>=lo) && (6-lo<ZT);

        #pragma unroll 1
        for (int dy = 0; dy < 7; ++dy){
            const int r   = y + dy;
            const int key = r & 7;
            const float* Pm = FLf + cur*SLICE_F + r*32;
            const float* Pa = Pm + PLANE_F;
            const float* Pb = Pa + PLANE_F;
            const int c0 = (max(2*xg-1, 0)      ^ key) * 4;
            const int c1 = ((2*xg)              ^ key) * 4;
            const int c2 = ((2*xg+1)            ^ key) * 4;
            const int c3 = (min(2*xg+2, 7)      ^ key) * 4;
            const float4 M0 = *(const float4*)(Pm + c0);
            const float4 M1 = *(const float4*)(Pm + c1);
            const float4 M2 = *(const float4*)(Pm + c2);
            const float4 M3 = *(const float4*)(Pm + c3);
            const float pm1 = lo_inv ? 0.f : M0.y;
            const float pm2 = lo_inv ? 0.f : M0.z;
            const float pm3 = lo_inv ? 0.f : M0.w;
            const float pm4 = M1.x, pm5 = M1.y, pm6 = M1.z, pm7 = M1.w;
            const float pm8 = M2.x, pm9 = M2.y, pm10 = M2.z, pm11 = M2.w;
            const float pm12 = hi_inv ? 0.f : M3.x;
            const float pm13 = hi_inv ? 0.f : M3.y;
            const float pm14 = hi_inv ? 0.f : M3.z;

            {   // t = 0: field mask*mx
                const float4 A0 = *(const float4*)(Pa + c0);
                const float4 A1 = *(const float4*)(Pa + c1);
                const float4 A2 = *(const float4*)(Pa + c2);
                const float4 A3 = *(const float4*)(Pa + c3);
                const float pa1 = pm1*A0.y,  pa2 = pm2*A0.z,  pa3 = pm3*A0.w;
                const float pa4 = pm4*A1.x,  pa5 = pm5*A1.y,  pa6 = pm6*A1.z,  pa7 = pm7*A1.w;
                const float pa8 = pm8*A2.x,  pa9 = pm9*A2.y,  pa10 = pm10*A2.z, pa11 = pm11*A2.w;
                const float pa12 = pm12*A3.x, pa13 = pm13*A3.y, pa14 = pm14*A3.z;
                TGROUP(pa, wcls)
            }
            {   // t = 1: field mask*Mx
                const float4 B0 = *(const float4*)(Pb + c0);
                const float4 B1 = *(const float4*)(Pb + c1);
                const float4 B2 = *(const float4*)(Pb + c2);
                const float4 B3 = *(const float4*)(Pb + c3);
                const float pb1 = pm1*B0.y,  pb2 = pm2*B0.z,  pb3 = pm3*B0.w;
                const float pb4 = pm4*B1.x,  pb5 = pm5*B1.y,  pb6 = pm6*B1.z,  pb7 = pm7*B1.w;
                const float pb8 = pm8*B2.x,  pb9 = pm9*B2.y,  pb10 = pm10*B2.z, pb11 = pm11*B2.w;
                const float pb12 = pm12*B3.x, pb13 = pm13*B3.y, pb14 = pm14*B3.z;
                TGROUP(pb, wcls + 343)
            }
            // t = 2: field mask
            TGROUP(pm, wcls + 686)
        }

        // store completed output plane zo = zi-3 (raw accumulator)
        if (zi >= z0 + 3){
            const int oidx = ((zi-3)*HH + (y0 + y))*WW + x0;
            *(float4*)(Gc + oidx)     = a0l;
            *(float4*)(Gc + oidx + 4) = a0h;
        }
        a0l=a1l; a0h=a1h; a1l=a2l; a1h=a2h; a2l=a3l; a2h=a3h;
        a3l=a4l; a3h=a4h; a4l=a5l; a4h=a5h; a5l=a6l; a5h=a6h;
        a6l = make_float4(0.f,0.f,0.f,0.f);
        a6h = make_float4(0.f,0.f,0.f,0.f);

        __builtin_amdgcn_s_barrier();            // all waves done reading buf[cur]
        __builtin_amdgcn_sched_barrier(0);
        issue_slice(mk, mxp, Mxp, FLf, cur*SLICE_F, zi+2, y0, lane, wid);  // prefetch (dummy past end)
        cur ^= 1;
    }
    asm volatile("s_waitcnt vmcnt(0)" ::: "memory");  // drain dummy DMA before LDS dealloc
}

// ---- sigmoid + heat min/max + ma write (BW-bound finalize of conv) ----
__global__ __launch_bounds__(256) void k_heat(const float* __restrict__ masks,
        const float* __restrict__ mx, float* G, unsigned* __restrict__ keys)
{
    __shared__ float r4[8];
    const int i = blockIdx.y;
    const int tid = threadIdx.x;
    const size_t v4 = (size_t)blockIdx.x*256 + tid;
    float4 acc = ((const float4*)(G + (size_t)i*VOX))[v4];
    float4 m4  = ((const float4*)(masks + (size_t)i*VOX))[v4];
    float4 x4  = ((const float4*)mx)[v4];
    float4 ma;
    ma.x = m4.x/(1.f + expf(-acc.x));
    ma.y = m4.y/(1.f + expf(-acc.y));
    ma.z = m4.z/(1.f + expf(-acc.z));
    ma.w = m4.w/(1.f + expf(-acc.w));
    ((float4*)(G + (size_t)i*VOX))[v4] = ma;
    float h0 = ma.x*x4.x, h1 = ma.y*x4.y, h2 = ma.z*x4.z, h3 = ma.w*x4.w;
    float hmn = fminf(fminf(h0,h1), fminf(h2,h3));
    float hmx = fmaxf(fmaxf(h0,h1), fmaxf(h2,h3));
    #pragma unroll
    for (int off = 32; off > 0; off >>= 1){
        hmn = fminf(hmn, __shfl_xor(hmn, off));
        hmx = fmaxf(hmx, __shfl_xor(hmx, off));
    }
    if ((tid & 63) == 0){ r4[(tid>>6)*2] = hmn; r4[(tid>>6)*2+1] = hmx; }
    __syncthreads();
    if (tid == 0){
        float a = fminf(fminf(r4[0],r4[2]), fminf(r4[4],r4[6]));
        float b = fmaxf(fmaxf(r4[1],r4[3]), fmaxf(r4[5],r4[7]));
        atomicMin(&keys[i],     keyOf(a));
        atomicMax(&keys[NCL+i], keyOf(b));
    }
}

__global__ void k_thr(const unsigned* __restrict__ keys, float* __restrict__ hminA,
                      float* __restrict__ invR){
    int i = threadIdx.x;
    if (i < NCL){
        float hm = keyInv(keys[i]);
        float hM = keyInv(keys[NCL+i]);
        hminA[i] = hm;
        invR[i] = 1.f/(hM - hm);
    }
}

// ---- g = ma * (norm > 0.2), in place ----
__global__ __launch_bounds__(256) void k_region(float* G, const float* __restrict__ mx,
        const float* __restrict__ hminA, const float* __restrict__ invR)
{
    int i = blockIdx.y;
    int v = blockIdx.x*256 + threadIdx.x;
    float ma = G[i*VOX + v];
    float heat = ma * mx[v];
    float norm = (heat - hminA[i]) * invR[i];
    G[i*VOX + v] = (norm > THRESV) ? ma : 0.f;
}

// ---- per-(class,channel) sums S1 = sum x*g, S2 = sum (x*g)^2 ----
__global__ __launch_bounds__(256) void k_stats(const float* __restrict__ x,
        const float* G, float* __restrict__ part)
{
    int tid = threadIdx.x;
    int c = tid & 63, vg = tid >> 6;
    int v0 = blockIdx.x * 2048;
    float s1[NCL], s2[NCL];
    #pragma unroll
    for (int i=0;i<NCL;i++){ s1[i]=0.f; s2[i]=0.f; }
    const float* xc = x + c*VOX;
    for (int k=0;k<512;k++){
        int v = v0 + (k<<2) + vg;
        float xv = xc[v];
        #pragma unroll
        for (int i=0;i<NCL;i++){
            float p = xv * G[i*VOX + v];
            s1[i] += p;
            s2[i] = fmaf(p, p, s2[i]);
        }
    }
    __shared__ float red[4][64][2*NCL];
    #pragma unroll
    for (int i=0;i<NCL;i++){ red[vg][c][i] = s1[i]; red[vg][c][NCL+i] = s2[i]; }
    __syncthreads();
    if (vg == 0){
        float* dst = part + (size_t)blockIdx.x * (NCL*CCH*2);
        for (int i=0;i<NCL;i++){
            float a = red[0][c][i]+red[1][c][i]+red[2][c][i]+red[3][c][i];
            float b = red[0][c][NCL+i]+red[1][c][NCL+i]+red[2][c][NCL+i]+red[3][c][NCL+i];
            dst[i*CCH*2 + c*2 + 0] = a;
            dst[i*CCH*2 + c*2 + 1] = b;
        }
    }
}

// ---- finish stats: a = gamma*rinv, kc = beta - m*rinv*gamma ----
__global__ void k_params(const float* __restrict__ part, const float* __restrict__ gamma,
        const float* __restrict__ beta, float* __restrict__ aArr, float* __restrict__ kcArr)
{
    int i = blockIdx.x, c = threadIdx.x;
    float s1 = 0.f, s2 = 0.f;
    for (int b=0;b<256;b++){
        const float* p = part + (size_t)b*(NCL*CCH*2) + i*CCH*2 + c*2;
        s1 += p[0]; s2 += p[1];
    }
    float m   = s1 * (1.f/(float)VOX);
    float var = s2 * (1.f/(float)VOX) - m*m;
    float rinv = 1.f/sqrtf(var + EPSV);
    float gm = gamma[c];
    aArr[i*CCH + c]  = gm*rinv;
    kcArr[i*CCH + c] = beta[c] - m*rinv*gm;
}

__global__ void k_kcol(const float* __restrict__ kcArr, float* __restrict__ KcA){
    int c = threadIdx.x;
    if (c < CCH){
        float s = 0.f;
        for (int i=0;i<NCL;i++) s += kcArr[i*CCH + c];
        KcA[c] = s;
    }
}

// ---- final: out[c,v] = relu( x*Sum_i g_i*a_ic + K[c] ), in-place over d_out ----
__global__ __launch_bounds__(256) void k_final(const float* __restrict__ x,
        float* outAll, const float* __restrict__ aArr, const float* __restrict__ KcA)
{
    __shared__ float aL[NCL*CCH];
    __shared__ float KL[CCH];
    int tid = threadIdx.x;
    for (int q=tid; q<NCL*CCH; q+=256) aL[q] = aArr[q];
    if (tid < CCH) KL[tid] = KcA[tid];
    __syncthreads();
    int v = blockIdx.x*256 + tid;
    const float* Gp = outAll + (size_t)NCL*VOX;
    float g[NCL];
    #pragma unroll
    for (int i=0;i<NCL;i++) g[i] = Gp[i*VOX + v];
    #pragma unroll 4
    for (int c=0;c<CCH;c++){
        float P = 0.f;
        #pragma unroll
        for (int i=0;i<NCL;i++) P = fmaf(g[i], aL[i*CCH + c], P);
        float xv = x[c*VOX + v];
        outAll[c*VOX + v] = fmaxf(0.f, fmaf(xv, P, KL[c]));
    }
}

extern "C" void kernel_launch(void* const* d_in, const int* in_sizes, int n_in,
                              void* d_out, int out_size, void* d_ws, size_t ws_size,
                              hipStream_t stream)
{
    const float* x     = (const float*)d_in[0];
    const float* clsw  = (const float*)d_in[1];
    const float* clsb  = (const float*)d_in[2];
    const float* cfr   = (const float*)d_in[3];
    const float* gamma = (const float*)d_in[4];
    const float* beta  = (const float*)d_in[5];

    float* out   = (float*)d_out;
    float* logit = out + (size_t)CCH*VOX;     // second output
    float* masks = out;                       // scratch: out[0 .. 20V)
    float* G     = out + (size_t)NCL*VOX;     // scratch: out[20V .. 40V)

    float* ws    = (float*)d_ws;
    float* mxp   = ws;                        // V
    float* Mxp   = ws + VOX;                  // V
    unsigned* keys = (unsigned*)(ws + 2*(size_t)VOX);   // 40
    float* hminA = ws + 2*(size_t)VOX + 64;   // 20
    float* invR  = hminA + NCL;               // 20
    float* part  = ws + 2*(size_t)VOX + 128;  // 256*2560
    float* aArr  = part + 256*(NCL*CCH*2);    // 1280
    float* kcArr = aArr + NCL*CCH;            // 1280
    float* KcA   = kcArr + NCL*CCH;           // 64

    k_init<<<1, 64, 0, stream>>>(keys);
    k_logit_softmax<<<VOX/256, 256, 0, stream>>>(x, clsw, clsb, masks, logit, mxp, Mxp);
    k_conv6<<<dim3(NCL, 16, 4), 128, 0, stream>>>(masks, mxp, Mxp, cfr, G);
    k_heat<<<dim3(VOX/1024, NCL), 256, 0, stream>>>(masks, mxp, G, keys);
    k_thr<<<1, 32, 0, stream>>>(keys, hminA, invR);
    k_region<<<dim3(VOX/256, NCL), 256, 0, stream>>>(G, mxp, hminA, invR);
    k_stats<<<256, 256, 0, stream>>>(x, G, part);
    k_params<<<NCL, CCH, 0, stream>>>(part, gamma, beta, aArr, kcArr);
    k_kcol<<<1, CCH, 0, stream>>>(kcArr, KcA);
    k_final<<<VOX/256, 256, 0, stream>>>(x, out, aArr, KcA);
}